// Round 1
// baseline (28.747 us; speedup 1.0000x reference)
//
#include <hip/hip_runtime.h>
#include <math.h>

#define NB 128   // batch
#define NL 16    // num_site
#define NM 32    // M
#define NP 4     // P
#define NMP 128  // M*P

// Kernel 1: one block per batch element b.
// Computes amp[b] = sum_j coef[j] * prod_l cos(u[l][j])
// and norm[b] = sum_{j,k} coef[j]coef[k] * prod_l (c[l][j]c[l][k] + s[l][j]s[l][k])
// where u[l][j] = theta[l][j] + sf[p(j)] * ds[b][l],  j = m*P+p.
// Writes perb[b] = -log(amp^2/norm + 1e-20).
__global__ __launch_bounds__(256) void per_b_kernel(
    const float* __restrict__ ds, const float* __restrict__ theta,
    const float* __restrict__ coef, float* __restrict__ perb)
{
    const int b = blockIdx.x;
    const int t = threadIdx.x;

    __shared__ float2 cs[NL][NMP];   // (cos, sin) of u
    __shared__ float  co[NMP];
    __shared__ float  dsrow[NL];
    __shared__ float  ra[256], rn[256];

    if (t < NL)  dsrow[t] = ds[b * NL + t];
    if (t < NMP) co[t]    = coef[t];
    __syncthreads();

    // 2048 sincos evaluations, 8 per thread
    for (int i = t; i < NL * NMP; i += 256) {
        int l = i >> 7;
        int j = i & (NMP - 1);
        int p = j & 3;
        float sf = (float)M_PI / (float)(2 << p);   // pi / 2^(p+1)
        float u  = theta[i] + sf * dsrow[l];
        float ss, cc;
        sincosf(u, &ss, &cc);
        cs[l][j] = make_float2(cc, ss);
    }
    __syncthreads();

    // amp partial: threads 0..127 each own one j
    float amp_part = 0.f;
    if (t < NMP) {
        float pr = co[t];
        #pragma unroll
        for (int l = 0; l < NL; ++l) pr *= cs[l][t].x;
        amp_part = pr;
    }

    // normalization partials: 16384 (j,k) pairs, 64 per thread.
    // Within a wave, j is uniform (LDS broadcast) and k is consecutive.
    float norm_part = 0.f;
    for (int pi = t; pi < NMP * NMP; pi += 256) {
        int j = pi >> 7;
        int k = pi & (NMP - 1);
        float pp = co[j] * co[k];
        #pragma unroll
        for (int l = 0; l < NL; ++l) {
            float2 a  = cs[l][j];
            float2 bb = cs[l][k];
            pp *= fmaf(a.x, bb.x, a.y * bb.y);  // cos(u_j - u_k)
        }
        norm_part += pp;
    }

    ra[t] = amp_part;
    rn[t] = norm_part;
    __syncthreads();
    for (int off = 128; off > 0; off >>= 1) {
        if (t < off) { ra[t] += ra[t + off]; rn[t] += rn[t + off]; }
        __syncthreads();
    }
    if (t == 0) {
        float amp = ra[0];
        float nrm = rn[0];
        perb[b] = -logf(amp * amp / nrm + 1e-20f);
    }
}

// Kernel 2: single block. mean(-log) + 0.01*(var(coef) + mean var_m(theta) + mean var_p(theta))
__global__ __launch_bounds__(256) void finalize_kernel(
    const float* __restrict__ perb, const float* __restrict__ theta,
    const float* __restrict__ coef, float* __restrict__ out)
{
    const int t = threadIdx.x;
    __shared__ float r1[256], r2[256];
    __shared__ float s_mnl, s_csum, s_csum2, s_vm;

    // pass 1: sum of per-b neg-logs, sum of coef
    r1[t] = (t < NB) ? perb[t] : 0.f;
    float cv = (t < NMP) ? coef[t] : 0.f;
    r2[t] = cv;
    __syncthreads();
    for (int off = 128; off > 0; off >>= 1) {
        if (t < off) { r1[t] += r1[t + off]; r2[t] += r2[t + off]; }
        __syncthreads();
    }
    if (t == 0) { s_mnl = r1[0] / (float)NB; s_csum = r2[0]; }
    __syncthreads();

    // pass 2: sum of coef^2, and reg_theta_m partials (64 (l,p) items, var over M, ddof=1)
    r1[t] = cv * cv;
    float vm = 0.f;
    if (t < NL * NP) {
        int l = t >> 2, p = t & 3;
        float sum = 0.f, sum2 = 0.f;
        for (int m = 0; m < NM; ++m) {
            float x = theta[(l * NM + m) * NP + p];
            sum += x; sum2 += x * x;
        }
        vm = (sum2 - sum * sum / (float)NM) / (float)(NM - 1);
    }
    r2[t] = vm;
    __syncthreads();
    for (int off = 128; off > 0; off >>= 1) {
        if (t < off) { r1[t] += r1[t + off]; r2[t] += r2[t + off]; }
        __syncthreads();
    }
    if (t == 0) { s_csum2 = r1[0]; s_vm = r2[0] / (float)(NL * NP); }
    __syncthreads();

    // pass 3: reg_theta_p (512 (l,m) items, var over P=4 contiguous values, ddof=1)
    float vp = 0.f;
    for (int i = t; i < NL * NM; i += 256) {
        const float* base = theta + i * NP;
        float sum = 0.f, sum2 = 0.f;
        #pragma unroll
        for (int p = 0; p < NP; ++p) { float x = base[p]; sum += x; sum2 += x * x; }
        vp += (sum2 - sum * sum / (float)NP) / (float)(NP - 1);
    }
    r1[t] = vp;
    __syncthreads();
    for (int off = 128; off > 0; off >>= 1) {
        if (t < off) r1[t] += r1[t + off];
        __syncthreads();
    }
    if (t == 0) {
        float reg_tp = r1[0] / (float)(NL * NM);
        float reg_c  = (s_csum2 - s_csum * s_csum / (float)NMP) / (float)(NMP - 1);
        out[0] = s_mnl + 0.01f * reg_c + 0.01f * s_vm + 0.01f * reg_tp;
    }
}

extern "C" void kernel_launch(void* const* d_in, const int* in_sizes, int n_in,
                              void* d_out, int out_size, void* d_ws, size_t ws_size,
                              hipStream_t stream) {
    const float* ds    = (const float*)d_in[0];  // (B, L)
    const float* theta = (const float*)d_in[1];  // (L, M, P)
    const float* coef  = (const float*)d_in[2];  // (M, P)
    float* perb = (float*)d_ws;                  // 128 floats scratch
    float* out  = (float*)d_out;

    per_b_kernel<<<NB, 256, 0, stream>>>(ds, theta, coef, perb);
    finalize_kernel<<<1, 256, 0, stream>>>(perb, theta, coef, out);
}

// Round 2
// 15.151 us; speedup vs baseline: 1.8974x; 1.8974x over previous
//
#include <hip/hip_runtime.h>
#include <math.h>

#define NB 128   // batch
#define NL 16    // num_site
#define NM 32    // M
#define NP 4     // P
#define NMP 128  // M*P

// Kernel 1: 2 blocks per batch element b (each owns a 64-wide k-half).
// 512 threads: thread t owns j = t&127 (row in registers), k-chunk kq = t>>7.
// norm partial -> wnorm[b*2+h]; amp -> wamp[b] (from h==0).
__global__ __launch_bounds__(512) void per_b_kernel(
    const float* __restrict__ ds, const float* __restrict__ theta,
    const float* __restrict__ coef, float* __restrict__ wnorm,
    float* __restrict__ wamp)
{
    const int b = blockIdx.x >> 1;
    const int h = blockIdx.x & 1;
    const int t = threadIdx.x;

    __shared__ float2 cs[NL][NMP];   // (cos, sin) of u[l][j]
    __shared__ float  co[NMP];
    __shared__ float  dsrow[NL];
    __shared__ float  redN[8], redA[8];

    if (t < NL)  dsrow[t] = ds[b * NL + t];
    if (t < NMP) co[t]    = coef[t];
    __syncthreads();

    // 2048 sincos, 4 per thread
    for (int i = t; i < NL * NMP; i += 512) {
        int l = i >> 7;
        int j = i & (NMP - 1);
        int p = j & 3;
        float sf = (float)M_PI / (float)(2 << p);   // pi / 2^(p+1)
        float u  = theta[i] + sf * dsrow[l];
        float ss, cc;
        sincosf(u, &ss, &cc);
        cs[l][j] = make_float2(cc, ss);
    }
    __syncthreads();

    const int j  = t & (NMP - 1);
    const int kq = t >> 7;              // 0..3
    const int k0 = h * 64 + kq * 16;

    // j-row into registers (32 VGPRs)
    float rc[NL], rs[NL];
    #pragma unroll
    for (int l = 0; l < NL; ++l) { float2 v = cs[l][j]; rc[l] = v.x; rs[l] = v.y; }

    const float wj = co[j];

    // amp partial: one thread per j, in block h==0 only
    float amp_part = 0.f;
    if (h == 0 && kq == 0) {
        float pr = wj;
        #pragma unroll
        for (int l = 0; l < NL; ++l) pr *= rc[l];
        amp_part = pr;
    }

    // 16 pairs per thread; k uniform across the wave -> LDS broadcast reads
    float norm_part = 0.f;
    #pragma unroll 4
    for (int ki = 0; ki < 16; ++ki) {
        int k = k0 + ki;
        float pp = wj * co[k];
        #pragma unroll
        for (int l = 0; l < NL; ++l) {
            float2 v = cs[l][k];
            pp *= fmaf(rc[l], v.x, rs[l] * v.y);   // cos(u_j - u_k)
        }
        norm_part += pp;
    }

    // wave64 butterfly reduce
    #pragma unroll
    for (int off = 32; off > 0; off >>= 1) {
        norm_part += __shfl_xor(norm_part, off);
        amp_part  += __shfl_xor(amp_part,  off);
    }
    const int wid  = t >> 6;
    const int lane = t & 63;
    if (lane == 0) { redN[wid] = norm_part; redA[wid] = amp_part; }
    __syncthreads();
    if (t == 0) {
        float n = 0.f, a = 0.f;
        #pragma unroll
        for (int w = 0; w < 8; ++w) { n += redN[w]; a += redA[w]; }
        wnorm[b * 2 + h] = n;
        if (h == 0) wamp[b] = a;
    }
}

// Kernel 2: single block. mean(-log(amp^2/norm + eps)) + 0.01*(reg_c + reg_tm + reg_tp)
__global__ __launch_bounds__(256) void finalize_kernel(
    const float* __restrict__ wnorm, const float* __restrict__ wamp,
    const float* __restrict__ theta, const float* __restrict__ coef,
    float* __restrict__ out)
{
    const int t = threadIdx.x;
    __shared__ float r1[256], r2[256];
    __shared__ float s_mnl, s_csum, s_csum2, s_vm;

    // pass 1: per-b neg-logs, sum of coef
    float mnl = 0.f;
    if (t < NB) {
        float a = wamp[t];
        float n = wnorm[2 * t] + wnorm[2 * t + 1];
        mnl = -logf(a * a / n + 1e-20f);
    }
    r1[t] = mnl;
    float cv = (t < NMP) ? coef[t] : 0.f;
    r2[t] = cv;
    __syncthreads();
    for (int off = 128; off > 0; off >>= 1) {
        if (t < off) { r1[t] += r1[t + off]; r2[t] += r2[t + off]; }
        __syncthreads();
    }
    if (t == 0) { s_mnl = r1[0] / (float)NB; s_csum = r2[0]; }
    __syncthreads();

    // pass 2: sum coef^2, reg_theta_m (var over M per (l,p), ddof=1)
    r1[t] = cv * cv;
    float vm = 0.f;
    if (t < NL * NP) {
        int l = t >> 2, p = t & 3;
        float sum = 0.f, sum2 = 0.f;
        for (int m = 0; m < NM; ++m) {
            float x = theta[(l * NM + m) * NP + p];
            sum += x; sum2 += x * x;
        }
        vm = (sum2 - sum * sum / (float)NM) / (float)(NM - 1);
    }
    r2[t] = vm;
    __syncthreads();
    for (int off = 128; off > 0; off >>= 1) {
        if (t < off) { r1[t] += r1[t + off]; r2[t] += r2[t + off]; }
        __syncthreads();
    }
    if (t == 0) { s_csum2 = r1[0]; s_vm = r2[0] / (float)(NL * NP); }
    __syncthreads();

    // pass 3: reg_theta_p (var over P=4 contiguous, ddof=1)
    float vp = 0.f;
    for (int i = t; i < NL * NM; i += 256) {
        const float* base = theta + i * NP;
        float sum = 0.f, sum2 = 0.f;
        #pragma unroll
        for (int p = 0; p < NP; ++p) { float x = base[p]; sum += x; sum2 += x * x; }
        vp += (sum2 - sum * sum / (float)NP) / (float)(NP - 1);
    }
    r1[t] = vp;
    __syncthreads();
    for (int off = 128; off > 0; off >>= 1) {
        if (t < off) r1[t] += r1[t + off];
        __syncthreads();
    }
    if (t == 0) {
        float reg_tp = r1[0] / (float)(NL * NM);
        float reg_c  = (s_csum2 - s_csum * s_csum / (float)NMP) / (float)(NMP - 1);
        out[0] = s_mnl + 0.01f * reg_c + 0.01f * s_vm + 0.01f * reg_tp;
    }
}

extern "C" void kernel_launch(void* const* d_in, const int* in_sizes, int n_in,
                              void* d_out, int out_size, void* d_ws, size_t ws_size,
                              hipStream_t stream) {
    const float* ds    = (const float*)d_in[0];  // (B, L)
    const float* theta = (const float*)d_in[1];  // (L, M, P)
    const float* coef  = (const float*)d_in[2];  // (M, P)
    float* wnorm = (float*)d_ws;                 // 256 floats
    float* wamp  = (float*)d_ws + 2 * NB;        // 128 floats
    float* out   = (float*)d_out;

    per_b_kernel<<<2 * NB, 512, 0, stream>>>(ds, theta, coef, wnorm, wamp);
    finalize_kernel<<<1, 256, 0, stream>>>(wnorm, wamp, theta, coef, out);
}